// Round 7
// baseline (1293.610 us; speedup 1.0000x reference)
//
#include <hip/hip_runtime.h>
#include <hip/hip_bf16.h>

// Problem constants
#define NTOT 65536      // B*N
#define KNN  20
#define CKEEP 32        // kept candidates for exact re-rank (margin over 20)
#define CAPB 384        // candidate rows: 96 + 256 worst-case + 32 stash
#define BPAD 65         // padded row width -> scan bank = (j+q)%32
#define HEADROOM 96     // compact when cnt > HEADROOM
#define KROW 104        // bf16 kf row stride (67 dims + pad)

typedef __attribute__((ext_vector_type(4))) float f32x4;
typedef __attribute__((ext_vector_type(8))) short s16x8;

// ws layout (bytes): kfB bf16[65536][104] | normB f32[65536] | nbr i32
#define WS_NORM 13631488
#define WS_NBR  13893632

// k_knn LDS map (bytes)
#define SMEM_KSQ 53248      // ksB @0 (53248), ksq @53248 (1024); scratch region [0,58880)
#define SMEM_BUF 58880      // unsigned buf[384][65] = 99840
#define SMEM_CNT 158720     // int cnt[64]
#define SMEM_TAU 158976     // float tau[64]
#define SMEM_SZ  159232
// re-rank overlay on scratch [0,58880): qkf dbl[64][67] @0 | rrD dbl[64][32] @34304 | rrI i32[64][32] @50688

__device__ __forceinline__ unsigned short f2bf_rne(float v){
  unsigned u = __float_as_uint(v);
  return (unsigned short)((u + 0x7FFFu + ((u >> 16) & 1u)) >> 16);
}

// ---------------------------------------------------------------------------
// k_prep: kf = [s(16), R^T v(48), pos(3)] -> bf16 rows (stride 104) + f32 norm
// ---------------------------------------------------------------------------
__global__ __launch_bounds__(256) void k_prep(const float* __restrict__ x,
        const float* __restrict__ pos, const float* __restrict__ lfr,
        unsigned short* __restrict__ kfB, float* __restrict__ normB){
  int n = blockIdx.x * 256 + threadIdx.x;
  const float* xr = x + n * 64;
  float R[9];
  #pragma unroll
  for (int j = 0; j < 9; j++) R[j] = lfr[n * 9 + j];
  float c[67];
  #pragma unroll
  for (int i = 0; i < 16; i++) c[i] = xr[i];
  #pragma unroll
  for (int k = 0; k < 16; k++){
    float v0 = xr[16 + 3*k], v1 = xr[17 + 3*k], v2 = xr[18 + 3*k];
    #pragma unroll
    for (int a = 0; a < 3; a++)
      c[16 + 3*k + a] = R[a] * v0 + R[3 + a] * v1 + R[6 + a] * v2;  // R^T v
  }
  #pragma unroll
  for (int a = 0; a < 3; a++) c[64 + a] = pos[n * 3 + a];
  float sq = 0.f;
  #pragma unroll
  for (int d = 0; d < 67; d++) sq += c[d] * c[d];
  __attribute__((aligned(16))) unsigned short row[KROW];
  #pragma unroll
  for (int d = 0; d < 67; d++) row[d] = f2bf_rne(c[d]);
  #pragma unroll
  for (int d = 67; d < KROW; d++) row[d] = 0;
  uint4* dst = (uint4*)(kfB + (size_t)n * KROW);
  const uint4* s4 = (const uint4*)row;
  #pragma unroll
  for (int i = 0; i < 13; i++) dst[i] = s4[i];
  normB[n] = sq;
}

// ---------------------------------------------------------------------------
// wave_compact: barrier-free exact top-32 for the wave's 8 queries.
// Lanes s=0..7 per query; chunked scan (bank-conflict-free); 32 rounds of
// masked min + shfl; stash kept entries at rows >= cmax, copy down to 0..31.
// ---------------------------------------------------------------------------
__device__ __forceinline__ void wave_compact(unsigned (*buf)[BPAD],
    int* cnt, float* tau, int lane, int wv, int cmax){
  int q = (wv << 3) + (lane >> 3);
  int s = lane & 7;
  int cn = cnt[q];
  int mN = (cmax + 7) >> 3;          // chunk size (wave-uniform)
  int lo = s * mN;
  unsigned long long mask = 0ull;
  unsigned last = 0xFFFFFFFFu;
  #pragma unroll 1
  for (int r = 0; r < 32; r++){
    unsigned vmin = 0xFFFFFFFFu; int imin = -1;
    #pragma unroll 1
    for (int i = 0; i < mN; i++){
      int j = lo + i;
      unsigned v = (j < cn) ? buf[j][q] : 0xFFFFFFFFu;
      if (!((mask >> i) & 1ull) && v < vmin){ vmin = v; imin = i; }
    }
    unsigned bv = vmin;
    #pragma unroll
    for (int off = 1; off < 8; off <<= 1){
      unsigned ov = (unsigned)__shfl_xor((int)bv, off, 64);
      bv = (ov < bv) ? ov : bv;
    }
    if (vmin == bv && imin >= 0 && bv != 0xFFFFFFFFu) mask |= (1ull << (unsigned)imin);
    last = bv;
  }
  int kc = __popcll(mask);
  int incl = kc;
  #pragma unroll
  for (int d = 1; d < 8; d <<= 1){
    int t = __shfl_up(incl, d, 8);
    if (s >= d) incl += t;
  }
  int wr = cmax + (incl - kc);       // exclusive prefix over the 8 lanes
  #pragma unroll 1
  for (int i = 0; i < mN; i++){
    if ((mask >> i) & 1ull){
      buf[wr][q] = buf[lo + i][q];   // dest >= cmax > all sources: disjoint
      wr++;
    }
  }
  __builtin_amdgcn_s_waitcnt(0);     // stash visible within wave
  #pragma unroll
  for (int r = s; r < 32; r += 8){
    unsigned v = buf[cmax + r][q];
    buf[r][q] = v;
  }
  if (s == 0){ cnt[q] = 32; tau[q] = __uint_as_float(last & 0xFFFFC000u); }
  __builtin_amdgcn_s_waitcnt(0);
}

// ---------------------------------------------------------------------------
// k_knn: MFMA bf16 coarse distances + streaming top-K + exact fp64 re-rank.
// 512 thr. Wave wv: all 4 m-tiles x n-tiles {2wv, 2wv+1}. 2 barriers/tile.
// Register prefetch of next tile's staging. Per-wave compaction.
// ---------------------------------------------------------------------------
__global__ __launch_bounds__(512, 2) void k_knn(
    const unsigned short* __restrict__ kfB, const float* __restrict__ normB,
    const float* __restrict__ x, const float* __restrict__ pos,
    const float* __restrict__ lfr, int* __restrict__ nbr){
  __shared__ __attribute__((aligned(16))) char smem[SMEM_SZ];
  unsigned short* ksB = (unsigned short*)(smem);
  float* ksq = (float*)(smem + SMEM_KSQ);
  unsigned (*buf)[BPAD] = (unsigned (*)[BPAD])(smem + SMEM_BUF);
  int* cnt = (int*)(smem + SMEM_CNT);
  float* tau = (float*)(smem + SMEM_TAU);

  int tid = threadIdx.x;
  int blk = blockIdx.x;
  int b = (blk & 7) >> 1;
  int w = ((blk >> 3) << 1) | (blk & 1);   // 0..63 within batch
  int bbase = b << 14;
  int q0 = w << 6;

  if (tid < 64){ cnt[tid] = 0; tau[tid] = 3.0e38f; }

  int lane = tid & 63;
  int wv = tid >> 6;
  int l15 = lane & 15, quad = lane >> 4;

  // A fragments (4 m-tiles x 3 k-steps) + query norms, once per block
  s16x8 afr[4][3];
  float qsqv[4][4];
  #pragma unroll
  for (int mt = 0; mt < 4; mt++){
    int nodeA = bbase + ((q0 + mt * 16 + l15) << 2);
    #pragma unroll
    for (int ks = 0; ks < 3; ks++)
      afr[mt][ks] = *(const s16x8*)(kfB + (size_t)nodeA * KROW + ks * 32 + quad * 8);
    #pragma unroll
    for (int r = 0; r < 4; r++)
      qsqv[mt][r] = normB[bbase + ((q0 + mt * 16 + quad * 4 + r) << 2)];
  }

  // prefetch tile 0 into registers (3328 uint4 total)
  uint4 pv[7]; float pn = 0.f;
  {
    const uint4* src = (const uint4*)(kfB + (size_t)bbase * KROW);
    #pragma unroll
    for (int k2 = 0; k2 < 7; k2++){ int i = tid + (k2 << 9); if (i < 3328) pv[k2] = src[i]; }
    if (tid < 256) pn = normB[bbase + tid];
  }
  __syncthreads();

  const unsigned long long SCHED =
      (1ull<<1)|(1ull<<3)|(1ull<<7)|(1ull<<15)|(1ull<<31)|(1ull<<47);

  for (int tile = 0; tile < 64; ++tile){
    // commit staged tile to LDS
    {
      uint4* dst = (uint4*)ksB;
      #pragma unroll
      for (int k2 = 0; k2 < 7; k2++){ int i = tid + (k2 << 9); if (i < 3328) dst[i] = pv[k2]; }
      if (tid < 256) ksq[tid] = pn;
    }
    __syncthreads();   // B1: staging + prior compacts visible
    // prefetch next tile (latency hidden behind compute)
    if (tile < 63){
      const uint4* src = (const uint4*)(kfB + (size_t)(bbase + ((tile + 1) << 8)) * KROW);
      #pragma unroll
      for (int k2 = 0; k2 < 7; k2++){ int i = tid + (k2 << 9); if (i < 3328) pv[k2] = src[i]; }
      if (tid < 256) pn = normB[bbase + ((tile + 1) << 8) + tid];
    }
    int kbase = tile << 8;

    float tauv[4][4];
    #pragma unroll
    for (int mt = 0; mt < 4; mt++)
      #pragma unroll
      for (int r = 0; r < 4; r++)
        tauv[mt][r] = tau[mt * 16 + quad * 4 + r];
    float ksqv[2];
    #pragma unroll
    for (int jn = 0; jn < 2; jn++)
      ksqv[jn] = ksq[(wv * 2 + jn) * 16 + l15];

    f32x4 acc[4][2];
    #pragma unroll
    for (int mt = 0; mt < 4; mt++){
      acc[mt][0] = (f32x4){0.f,0.f,0.f,0.f};
      acc[mt][1] = (f32x4){0.f,0.f,0.f,0.f};
    }
    #pragma unroll
    for (int ks = 0; ks < 3; ks++){
      s16x8 bfr[2];
      #pragma unroll
      for (int jn = 0; jn < 2; jn++){
        int n = (wv * 2 + jn) * 16 + l15;
        bfr[jn] = *(const s16x8*)(ksB + n * KROW + ks * 32 + quad * 8);
      }
      #pragma unroll
      for (int mt = 0; mt < 4; mt++)
        #pragma unroll
        for (int jn = 0; jn < 2; jn++)
          acc[mt][jn] = __builtin_amdgcn_mfma_f32_16x16x32_bf16(
              afr[mt][ks], bfr[jn], acc[mt][jn], 0, 0, 0);
    }

    // epilogue: d2 + threshold-stream append
    #pragma unroll
    for (int mt = 0; mt < 4; mt++){
      #pragma unroll
      for (int jn = 0; jn < 2; jn++){
        int kidx = kbase + (wv * 2 + jn) * 16 + l15;
        #pragma unroll
        for (int r = 0; r < 4; r++){
          float d2 = fmaxf(qsqv[mt][r] + ksqv[jn] - 2.f * acc[mt][jn][r], 0.f);
          if (d2 < tauv[mt][r]){
            int q = mt * 16 + quad * 4 + r;
            int pp = atomicAdd(&cnt[q], 1);
            buf[pp][q] = ((__float_as_uint(d2) + 0x2000u) & 0xFFFFC000u) | (unsigned)kidx;
          }
        }
      }
    }
    __syncthreads();   // B2: appends visible; ksB reads done
    // per-wave compact decision (no cross-wave sync needed)
    int cmax = cnt[(wv << 3) + (lane >> 3)];
    #pragma unroll
    for (int off = 8; off < 64; off <<= 1){
      int o = __shfl_xor(cmax, off, 64);
      cmax = o > cmax ? o : cmax;
    }
    if (cmax > HEADROOM || ((SCHED >> tile) & 1ull))
      wave_compact(buf, cnt, tau, lane, wv, cmax);
  }
  // final exact compact -> rows 0..31 = coarse top-32 per query
  {
    int cmax = cnt[(wv << 3) + (lane >> 3)];
    #pragma unroll
    for (int off = 8; off < 64; off <<= 1){
      int o = __shfl_xor(cmax, off, 64);
      cmax = o > cmax ? o : cmax;
    }
    wave_compact(buf, cnt, tau, lane, wv, cmax);
  }
  __syncthreads();

  // ---- exact fp64 re-rank of the 32 survivors (kf rebuilt from raw inputs) ----
  double* qkf = (double*)(smem);
  double* rrD = (double*)(smem + 34304);
  int*    rrI = (int*)(smem + 50688);

  {  // rebuild query kf in fp64
    int t8 = tid & 7, q = tid >> 3;
    int node = bbase + ((q0 + q) << 2);
    const float* xr = x + node * 64;
    for (int dd = t8; dd < 67; dd += 8){
      double val;
      if (dd < 16) val = (double)xr[dd];
      else if (dd < 64){
        int r = dd - 16; int k = r / 3; int a = r - 3 * k;
        val = (double)lfr[node*9 + a]     * (double)xr[16 + 3*k]
            + (double)lfr[node*9 + 3 + a] * (double)xr[17 + 3*k]
            + (double)lfr[node*9 + 6 + a] * (double)xr[18 + 3*k];
      } else val = (double)pos[node*3 + (dd - 64)];
      qkf[q * 67 + dd] = val;
    }
  }
  __syncthreads();
  {  // candidate d2 in fp64
    int t8 = tid & 7, q = tid >> 3;
    for (int j = t8; j < CKEEP; j += 8){
      int idx = (int)(buf[j][q] & 0x3FFFu);
      int node = bbase + idx;
      const float* xr = x + node * 64;
      double R[9];
      #pragma unroll
      for (int t = 0; t < 9; t++) R[t] = (double)lfr[node * 9 + t];
      double d2 = 0.0;
      #pragma unroll
      for (int dd = 0; dd < 16; dd++){ double t = (double)xr[dd] - qkf[q*67 + dd]; d2 += t * t; }
      #pragma unroll
      for (int k = 0; k < 16; k++){
        double v0 = xr[16 + 3*k], v1 = xr[17 + 3*k], v2 = xr[18 + 3*k];
        #pragma unroll
        for (int a = 0; a < 3; a++){
          double val = R[a] * v0 + R[3 + a] * v1 + R[6 + a] * v2;
          double t = val - qkf[q*67 + 16 + 3*k + a]; d2 += t * t;
        }
      }
      #pragma unroll
      for (int a = 0; a < 3; a++){ double t = (double)pos[node*3 + a] - qkf[q*67 + 64 + a]; d2 += t * t; }
      rrD[q * CKEEP + j] = d2; rrI[q * CKEEP + j] = idx;
    }
  }
  __syncthreads();
  if (tid < 64){
    int qq = tid;
    int qid = (b << 12) + q0 + qq;
    #pragma unroll 1
    for (int s = 0; s < KNN; s++){
      double best = rrD[qq * CKEEP + s]; int bi = s;
      for (int t = s + 1; t < CKEEP; t++){
        double v = rrD[qq * CKEEP + t]; if (v < best){ best = v; bi = t; }
      }
      double tv = rrD[qq * CKEEP + bi]; rrD[qq * CKEEP + bi] = rrD[qq * CKEEP + s]; rrD[qq * CKEEP + s] = tv;
      int ti = rrI[qq * CKEEP + bi]; rrI[qq * CKEEP + bi] = rrI[qq * CKEEP + s]; rrI[qq * CKEEP + s] = ti;
      nbr[qid * KNN + s] = bbase + rrI[qq * CKEEP + s];
    }
  }
}

// ---------------------------------------------------------------------------
// k_mlp: 2 queries/block (40 edges). Gather x_src, build h=[x_dst, rel_local],
// relu(h@W1+b1)@W2, max over edges, +b2, fp32 store.
// ---------------------------------------------------------------------------
__global__ __launch_bounds__(256) void k_mlp(const float* __restrict__ x,
    const float* __restrict__ lfr, const int* __restrict__ nbr,
    const float* __restrict__ W1, const float* __restrict__ b1,
    const float* __restrict__ W2, const float* __restrict__ b2,
    float* __restrict__ out){
  __shared__ float xs[40][64];
  __shared__ float h[40][128];
  __shared__ float a1[40][128];
  __shared__ float xdL[2][64];
  __shared__ float lfL[2][9];
  __shared__ int nbrL[40];

  int tid = threadIdx.x;
  int qid0 = blockIdx.x * 2;
  if (tid < 128){
    int ql = tid >> 6, d = tid & 63;
    int qid = qid0 + ql;
    int node = ((qid >> 12) << 14) + ((qid & 4095) << 2);
    xdL[ql][d] = x[node * 64 + d];
  } else if (tid < 146){
    int t = tid - 128; int ql = t / 9, j = t - 9 * ql;
    int qid = qid0 + ql;
    int node = ((qid >> 12) << 14) + ((qid & 4095) << 2);
    lfL[ql][j] = lfr[node * 9 + j];
  } else if (tid < 186){
    int t = tid - 146; int ql = t / 20, j = t - 20 * ql;
    nbrL[t] = nbr[(qid0 + ql) * 20 + j];
  }
  __syncthreads();
  #pragma unroll 1
  for (int p = 0; p < 10; p++){
    int e = (tid >> 6) + (p << 2), d = tid & 63;
    xs[e][d] = x[nbrL[e] * 64 + d];
  }
  __syncthreads();
  {
    int d = tid & 127;
    int cls, kk = 0, aa = 0;
    if (d < 64) cls = 0;
    else { int dd = d - 64;
      if (dd < 16) cls = 1;
      else { cls = 2; int r = dd - 16; kk = (r * 21846) >> 16; aa = r - 3 * kk; } }
    #pragma unroll 1
    for (int p = 0; p < 20; p++){
      int e = (tid >> 7) + (p << 1);
      int ql = (e >= 20) ? 1 : 0;
      float v;
      if (cls == 0) v = xdL[ql][d];
      else if (cls == 1) v = xs[e][d - 64] - xdL[ql][d - 64];
      else {
        int base = 16 + 3 * kk;
        float u0 = xs[e][base]     - xdL[ql][base];
        float u1 = xs[e][base + 1] - xdL[ql][base + 1];
        float u2 = xs[e][base + 2] - xdL[ql][base + 2];
        v = lfL[ql][aa * 3] * u0 + lfL[ql][aa * 3 + 1] * u1 + lfL[ql][aa * 3 + 2] * u2;
      }
      h[e][d] = v;
    }
  }
  __syncthreads();
  int eg = tid >> 7, og = tid & 127;
  {
    float acc1[20];
    float bv = b1[og];
    #pragma unroll
    for (int i = 0; i < 20; i++) acc1[i] = bv;
    for (int d0 = 0; d0 < 128; d0 += 4){
      float w0 = W1[(d0 + 0) * 128 + og];
      float w1 = W1[(d0 + 1) * 128 + og];
      float w2 = W1[(d0 + 2) * 128 + og];
      float w3 = W1[(d0 + 3) * 128 + og];
      #pragma unroll
      for (int i = 0; i < 20; i++){
        float4 hv = *(float4*)&h[eg * 20 + i][d0];
        acc1[i] += hv.x * w0 + hv.y * w1 + hv.z * w2 + hv.w * w3;
      }
    }
    #pragma unroll
    for (int i = 0; i < 20; i++) a1[eg * 20 + i][og] = fmaxf(acc1[i], 0.f);
  }
  __syncthreads();
  {
    float acc2[20];
    #pragma unroll
    for (int i = 0; i < 20; i++) acc2[i] = 0.f;
    for (int d0 = 0; d0 < 128; d0 += 4){
      float w0 = W2[(d0 + 0) * 128 + og];
      float w1 = W2[(d0 + 1) * 128 + og];
      float w2 = W2[(d0 + 2) * 128 + og];
      float w3 = W2[(d0 + 3) * 128 + og];
      #pragma unroll
      for (int i = 0; i < 20; i++){
        float4 av = *(float4*)&a1[eg * 20 + i][d0];
        acc2[i] += av.x * w0 + av.y * w1 + av.z * w2 + av.w * w3;
      }
    }
    float m = -3.0e38f;
    #pragma unroll
    for (int i = 0; i < 20; i++) m = fmaxf(m, acc2[i]);
    m += b2[og];
    out[(qid0 + eg) * 128 + og] = m;
  }
}

// ---------------------------------------------------------------------------
// k_tail: pos[idx], batch[idx], lframes[idx] as fp32 at flat offsets.
// ---------------------------------------------------------------------------
__global__ __launch_bounds__(256) void k_tail(const float* __restrict__ pos,
    const float* __restrict__ lfr, float* __restrict__ out){
  int q = blockIdx.x * 256 + threadIdx.x;   // 0..16383
  int b = q >> 12;
  int node = (b << 14) + ((q & 4095) << 2);
  float* o_pos = out + 2097152;    // 16384*128
  float* o_bat = out + 2146304;    // + 16384*3
  float* o_lf  = out + 2162688;    // + 16384
  #pragma unroll
  for (int j = 0; j < 3; j++) o_pos[q * 3 + j] = pos[node * 3 + j];
  o_bat[q] = (float)b;
  #pragma unroll
  for (int j = 0; j < 9; j++) o_lf[q * 9 + j] = lfr[node * 9 + j];
}

extern "C" void kernel_launch(void* const* d_in, const int* in_sizes, int n_in,
                              void* d_out, int out_size, void* d_ws, size_t ws_size,
                              hipStream_t stream){
  const float* x   = (const float*)d_in[0];
  const float* pos = (const float*)d_in[1];
  const float* lfr = (const float*)d_in[2];
  // d_in[3] = batch (recomputed analytically)
  const float* W1  = (const float*)d_in[4];
  const float* b1  = (const float*)d_in[5];
  const float* W2  = (const float*)d_in[6];
  const float* b2  = (const float*)d_in[7];

  unsigned short* kfB = (unsigned short*)d_ws;
  float* normB = (float*)((char*)d_ws + WS_NORM);
  int*   nbr   = (int*)((char*)d_ws + WS_NBR);
  float* out = (float*)d_out;

  hipLaunchKernelGGL(k_prep, dim3(256),  dim3(256), 0, stream, x, pos, lfr, kfB, normB);
  hipLaunchKernelGGL(k_knn,  dim3(256),  dim3(512), 0, stream, kfB, normB, x, pos, lfr, nbr);
  hipLaunchKernelGGL(k_mlp,  dim3(8192), dim3(256), 0, stream, x, lfr, nbr, W1, b1, W2, b2, out);
  hipLaunchKernelGGL(k_tail, dim3(64),   dim3(256), 0, stream, pos, lfr, out);
}

// Round 8
// 1289.617 us; speedup vs baseline: 1.0031x; 1.0031x over previous
//
#include <hip/hip_runtime.h>
#include <hip/hip_bf16.h>

// Problem constants
#define NTOT 65536      // B*N
#define KNN  20
#define CKEEP 32        // kept candidates for exact re-rank (margin over 20)
#define CAPB 384        // candidate rows: 96 + 256 worst-case + 32 stash
#define BPAD 65         // padded row width -> scan bank = (j+q)%32
#define HEADROOM 96     // compact when cnt > HEADROOM
#define KROW 104        // bf16 kf row stride (67 dims + pad)

typedef __attribute__((ext_vector_type(4))) float f32x4;
typedef __attribute__((ext_vector_type(8))) short s16x8;

// ws layout (bytes): kfB bf16[65536][104] | normB f32[65536] | nbr i32
#define WS_NORM 13631488
#define WS_NBR  13893632

// k_knn LDS map (bytes)
#define SMEM_KSQ 53248      // ksB @0 (53248), ksq @53248 (1024); scratch region [0,58880)
#define SMEM_BUF 58880      // unsigned buf[384][65] = 99840
#define SMEM_CNT 158720     // int cnt[64]
#define SMEM_TAU 158976     // float tau[64]
#define SMEM_SZ  159232
// re-rank overlay on scratch [0,58880): qkf dbl[64][67] @0 | rrD dbl[64][32] @34304 | rrI i32[64][32] @50688

__device__ __forceinline__ unsigned short f2bf_rne(float v){
  unsigned u = __float_as_uint(v);
  return (unsigned short)((u + 0x7FFFu + ((u >> 16) & 1u)) >> 16);
}

// ---------------------------------------------------------------------------
// k_prep: kf = [s(16), R^T v(48), pos(3)] -> bf16 rows (stride 104) + f32 norm
// ---------------------------------------------------------------------------
__global__ __launch_bounds__(256) void k_prep(const float* __restrict__ x,
        const float* __restrict__ pos, const float* __restrict__ lfr,
        unsigned short* __restrict__ kfB, float* __restrict__ normB){
  int n = blockIdx.x * 256 + threadIdx.x;
  const float* xr = x + n * 64;
  float R[9];
  #pragma unroll
  for (int j = 0; j < 9; j++) R[j] = lfr[n * 9 + j];
  float c[67];
  #pragma unroll
  for (int i = 0; i < 16; i++) c[i] = xr[i];
  #pragma unroll
  for (int k = 0; k < 16; k++){
    float v0 = xr[16 + 3*k], v1 = xr[17 + 3*k], v2 = xr[18 + 3*k];
    #pragma unroll
    for (int a = 0; a < 3; a++)
      c[16 + 3*k + a] = R[a] * v0 + R[3 + a] * v1 + R[6 + a] * v2;  // R^T v
  }
  #pragma unroll
  for (int a = 0; a < 3; a++) c[64 + a] = pos[n * 3 + a];
  float sq = 0.f;
  #pragma unroll
  for (int d = 0; d < 67; d++) sq += c[d] * c[d];
  __attribute__((aligned(16))) unsigned short row[KROW];
  #pragma unroll
  for (int d = 0; d < 67; d++) row[d] = f2bf_rne(c[d]);
  #pragma unroll
  for (int d = 67; d < KROW; d++) row[d] = 0;
  uint4* dst = (uint4*)(kfB + (size_t)n * KROW);
  const uint4* s4 = (const uint4*)row;
  #pragma unroll
  for (int i = 0; i < 13; i++) dst[i] = s4[i];
  normB[n] = sq;
}

// ---------------------------------------------------------------------------
// wave_compact: barrier-free exact top-32 for the wave's 8 queries.
// ---------------------------------------------------------------------------
__device__ __forceinline__ void wave_compact(unsigned (*buf)[BPAD],
    int* cnt, float* tau, int lane, int wv, int cmax){
  int q = (wv << 3) + (lane >> 3);
  int s = lane & 7;
  int cn = cnt[q];
  int mN = (cmax + 7) >> 3;          // chunk size (wave-uniform)
  int lo = s * mN;
  unsigned long long mask = 0ull;
  unsigned last = 0xFFFFFFFFu;
  #pragma unroll 1
  for (int r = 0; r < 32; r++){
    unsigned vmin = 0xFFFFFFFFu; int imin = -1;
    #pragma unroll 1
    for (int i = 0; i < mN; i++){
      int j = lo + i;
      unsigned v = (j < cn) ? buf[j][q] : 0xFFFFFFFFu;
      if (!((mask >> i) & 1ull) && v < vmin){ vmin = v; imin = i; }
    }
    unsigned bv = vmin;
    #pragma unroll
    for (int off = 1; off < 8; off <<= 1){
      unsigned ov = (unsigned)__shfl_xor((int)bv, off, 64);
      bv = (ov < bv) ? ov : bv;
    }
    if (vmin == bv && imin >= 0 && bv != 0xFFFFFFFFu) mask |= (1ull << (unsigned)imin);
    last = bv;
  }
  int kc = __popcll(mask);
  int incl = kc;
  #pragma unroll
  for (int d = 1; d < 8; d <<= 1){
    int t = __shfl_up(incl, d, 8);
    if (s >= d) incl += t;
  }
  int wr = cmax + (incl - kc);       // exclusive prefix over the 8 lanes
  #pragma unroll 1
  for (int i = 0; i < mN; i++){
    if ((mask >> i) & 1ull){
      buf[wr][q] = buf[lo + i][q];   // dest >= cmax > all sources: disjoint
      wr++;
    }
  }
  __builtin_amdgcn_s_waitcnt(0);     // stash visible within wave
  #pragma unroll
  for (int r = s; r < 32; r += 8){
    unsigned v = buf[cmax + r][q];
    buf[r][q] = v;
  }
  if (s == 0){ cnt[q] = 32; tau[q] = __uint_as_float(last & 0xFFFFC000u); }
  __builtin_amdgcn_s_waitcnt(0);
}

// ---------------------------------------------------------------------------
// k_knn: MFMA bf16 coarse distances + streaming top-K + exact fp64 re-rank.
// 512 thr, __launch_bounds__(512,1): LDS caps at 1 block/CU (2 waves/SIMD),
// so allow the full 256-VGPR/wave budget -- (512,2) was interpreted as
// 2 blocks/CU by the compiler -> 128-VGPR cap -> scratch spills (373 MB
// WRITE_SIZE in r7). Wave wv: 4 m-tiles x n-tiles {2wv,2wv+1}; 2 barriers/
// tile; register prefetch of next tile; per-wave barrier-free compaction.
// ---------------------------------------------------------------------------
__global__ __launch_bounds__(512, 1) void k_knn(
    const unsigned short* __restrict__ kfB, const float* __restrict__ normB,
    const float* __restrict__ x, const float* __restrict__ pos,
    const float* __restrict__ lfr, int* __restrict__ nbr){
  __shared__ __attribute__((aligned(16))) char smem[SMEM_SZ];
  unsigned short* ksB = (unsigned short*)(smem);
  float* ksq = (float*)(smem + SMEM_KSQ);
  unsigned (*buf)[BPAD] = (unsigned (*)[BPAD])(smem + SMEM_BUF);
  int* cnt = (int*)(smem + SMEM_CNT);
  float* tau = (float*)(smem + SMEM_TAU);

  int tid = threadIdx.x;
  int blk = blockIdx.x;
  int b = (blk & 7) >> 1;
  int w = ((blk >> 3) << 1) | (blk & 1);   // 0..63 within batch
  int bbase = b << 14;
  int q0 = w << 6;

  if (tid < 64){ cnt[tid] = 0; tau[tid] = 3.0e38f; }

  int lane = tid & 63;
  int wv = tid >> 6;
  int l15 = lane & 15, quad = lane >> 4;

  // A fragments (4 m-tiles x 3 k-steps) + query norms, once per block
  s16x8 afr[4][3];
  float qsqv[4][4];
  #pragma unroll
  for (int mt = 0; mt < 4; mt++){
    int nodeA = bbase + ((q0 + mt * 16 + l15) << 2);
    #pragma unroll
    for (int ks = 0; ks < 3; ks++)
      afr[mt][ks] = *(const s16x8*)(kfB + (size_t)nodeA * KROW + ks * 32 + quad * 8);
    #pragma unroll
    for (int r = 0; r < 4; r++)
      qsqv[mt][r] = normB[bbase + ((q0 + mt * 16 + quad * 4 + r) << 2)];
  }

  // prefetch tile 0 into registers (3328 uint4 total)
  uint4 pv[7]; float pn = 0.f;
  {
    const uint4* src = (const uint4*)(kfB + (size_t)bbase * KROW);
    #pragma unroll
    for (int k2 = 0; k2 < 7; k2++){ int i = tid + (k2 << 9); if (i < 3328) pv[k2] = src[i]; }
    if (tid < 256) pn = normB[bbase + tid];
  }
  __syncthreads();

  const unsigned long long SCHED =
      (1ull<<1)|(1ull<<3)|(1ull<<7)|(1ull<<15)|(1ull<<31)|(1ull<<47);

  for (int tile = 0; tile < 64; ++tile){
    // commit staged tile to LDS
    {
      uint4* dst = (uint4*)ksB;
      #pragma unroll
      for (int k2 = 0; k2 < 7; k2++){ int i = tid + (k2 << 9); if (i < 3328) dst[i] = pv[k2]; }
      if (tid < 256) ksq[tid] = pn;
    }
    __syncthreads();   // B1: staging + prior compacts visible
    // prefetch next tile (latency hidden behind compute)
    if (tile < 63){
      const uint4* src = (const uint4*)(kfB + (size_t)(bbase + ((tile + 1) << 8)) * KROW);
      #pragma unroll
      for (int k2 = 0; k2 < 7; k2++){ int i = tid + (k2 << 9); if (i < 3328) pv[k2] = src[i]; }
      if (tid < 256) pn = normB[bbase + ((tile + 1) << 8) + tid];
    }
    int kbase = tile << 8;

    float tauv[4][4];
    #pragma unroll
    for (int mt = 0; mt < 4; mt++)
      #pragma unroll
      for (int r = 0; r < 4; r++)
        tauv[mt][r] = tau[mt * 16 + quad * 4 + r];
    float ksqv[2];
    #pragma unroll
    for (int jn = 0; jn < 2; jn++)
      ksqv[jn] = ksq[(wv * 2 + jn) * 16 + l15];

    f32x4 acc[4][2];
    #pragma unroll
    for (int mt = 0; mt < 4; mt++){
      acc[mt][0] = (f32x4){0.f,0.f,0.f,0.f};
      acc[mt][1] = (f32x4){0.f,0.f,0.f,0.f};
    }
    #pragma unroll
    for (int ks = 0; ks < 3; ks++){
      s16x8 bfr[2];
      #pragma unroll
      for (int jn = 0; jn < 2; jn++){
        int n = (wv * 2 + jn) * 16 + l15;
        bfr[jn] = *(const s16x8*)(ksB + n * KROW + ks * 32 + quad * 8);
      }
      #pragma unroll
      for (int mt = 0; mt < 4; mt++)
        #pragma unroll
        for (int jn = 0; jn < 2; jn++)
          acc[mt][jn] = __builtin_amdgcn_mfma_f32_16x16x32_bf16(
              afr[mt][ks], bfr[jn], acc[mt][jn], 0, 0, 0);
    }

    // epilogue: d2 + threshold-stream append
    #pragma unroll
    for (int mt = 0; mt < 4; mt++){
      #pragma unroll
      for (int jn = 0; jn < 2; jn++){
        int kidx = kbase + (wv * 2 + jn) * 16 + l15;
        #pragma unroll
        for (int r = 0; r < 4; r++){
          float d2 = fmaxf(qsqv[mt][r] + ksqv[jn] - 2.f * acc[mt][jn][r], 0.f);
          if (d2 < tauv[mt][r]){
            int q = mt * 16 + quad * 4 + r;
            int pp = atomicAdd(&cnt[q], 1);
            buf[pp][q] = ((__float_as_uint(d2) + 0x2000u) & 0xFFFFC000u) | (unsigned)kidx;
          }
        }
      }
    }
    __syncthreads();   // B2: appends visible; ksB reads done
    // per-wave compact decision (no cross-wave sync needed)
    int cmax = cnt[(wv << 3) + (lane >> 3)];
    #pragma unroll
    for (int off = 8; off < 64; off <<= 1){
      int o = __shfl_xor(cmax, off, 64);
      cmax = o > cmax ? o : cmax;
    }
    if (cmax > HEADROOM || ((SCHED >> tile) & 1ull))
      wave_compact(buf, cnt, tau, lane, wv, cmax);
  }
  // final exact compact -> rows 0..31 = coarse top-32 per query
  {
    int cmax = cnt[(wv << 3) + (lane >> 3)];
    #pragma unroll
    for (int off = 8; off < 64; off <<= 1){
      int o = __shfl_xor(cmax, off, 64);
      cmax = o > cmax ? o : cmax;
    }
    wave_compact(buf, cnt, tau, lane, wv, cmax);
  }
  __syncthreads();

  // ---- exact fp64 re-rank of the 32 survivors (kf rebuilt from raw inputs) ----
  double* qkf = (double*)(smem);
  double* rrD = (double*)(smem + 34304);
  int*    rrI = (int*)(smem + 50688);

  {  // rebuild query kf in fp64
    int t8 = tid & 7, q = tid >> 3;
    int node = bbase + ((q0 + q) << 2);
    const float* xr = x + node * 64;
    for (int dd = t8; dd < 67; dd += 8){
      double val;
      if (dd < 16) val = (double)xr[dd];
      else if (dd < 64){
        int r = dd - 16; int k = r / 3; int a = r - 3 * k;
        val = (double)lfr[node*9 + a]     * (double)xr[16 + 3*k]
            + (double)lfr[node*9 + 3 + a] * (double)xr[17 + 3*k]
            + (double)lfr[node*9 + 6 + a] * (double)xr[18 + 3*k];
      } else val = (double)pos[node*3 + (dd - 64)];
      qkf[q * 67 + dd] = val;
    }
  }
  __syncthreads();
  {  // candidate d2 in fp64
    int t8 = tid & 7, q = tid >> 3;
    for (int j = t8; j < CKEEP; j += 8){
      int idx = (int)(buf[j][q] & 0x3FFFu);
      int node = bbase + idx;
      const float* xr = x + node * 64;
      double R[9];
      #pragma unroll
      for (int t = 0; t < 9; t++) R[t] = (double)lfr[node * 9 + t];
      double d2 = 0.0;
      #pragma unroll
      for (int dd = 0; dd < 16; dd++){ double t = (double)xr[dd] - qkf[q*67 + dd]; d2 += t * t; }
      #pragma unroll
      for (int k = 0; k < 16; k++){
        double v0 = xr[16 + 3*k], v1 = xr[17 + 3*k], v2 = xr[18 + 3*k];
        #pragma unroll
        for (int a = 0; a < 3; a++){
          double val = R[a] * v0 + R[3 + a] * v1 + R[6 + a] * v2;
          double t = val - qkf[q*67 + 16 + 3*k + a]; d2 += t * t;
        }
      }
      #pragma unroll
      for (int a = 0; a < 3; a++){ double t = (double)pos[node*3 + a] - qkf[q*67 + 64 + a]; d2 += t * t; }
      rrD[q * CKEEP + j] = d2; rrI[q * CKEEP + j] = idx;
    }
  }
  __syncthreads();
  if (tid < 64){
    int qq = tid;
    int qid = (b << 12) + q0 + qq;
    #pragma unroll 1
    for (int s = 0; s < KNN; s++){
      double best = rrD[qq * CKEEP + s]; int bi = s;
      for (int t = s + 1; t < CKEEP; t++){
        double v = rrD[qq * CKEEP + t]; if (v < best){ best = v; bi = t; }
      }
      double tv = rrD[qq * CKEEP + bi]; rrD[qq * CKEEP + bi] = rrD[qq * CKEEP + s]; rrD[qq * CKEEP + s] = tv;
      int ti = rrI[qq * CKEEP + bi]; rrI[qq * CKEEP + bi] = rrI[qq * CKEEP + s]; rrI[qq * CKEEP + s] = ti;
      nbr[qid * KNN + s] = bbase + rrI[qq * CKEEP + s];
    }
  }
}

// ---------------------------------------------------------------------------
// k_mlp: 2 queries/block (40 edges). Gather x_src, build h=[x_dst, rel_local],
// relu(h@W1+b1)@W2, max over edges, +b2, fp32 store.
// ---------------------------------------------------------------------------
__global__ __launch_bounds__(256) void k_mlp(const float* __restrict__ x,
    const float* __restrict__ lfr, const int* __restrict__ nbr,
    const float* __restrict__ W1, const float* __restrict__ b1,
    const float* __restrict__ W2, const float* __restrict__ b2,
    float* __restrict__ out){
  __shared__ float xs[40][64];
  __shared__ float h[40][128];
  __shared__ float a1[40][128];
  __shared__ float xdL[2][64];
  __shared__ float lfL[2][9];
  __shared__ int nbrL[40];

  int tid = threadIdx.x;
  int qid0 = blockIdx.x * 2;
  if (tid < 128){
    int ql = tid >> 6, d = tid & 63;
    int qid = qid0 + ql;
    int node = ((qid >> 12) << 14) + ((qid & 4095) << 2);
    xdL[ql][d] = x[node * 64 + d];
  } else if (tid < 146){
    int t = tid - 128; int ql = t / 9, j = t - 9 * ql;
    int qid = qid0 + ql;
    int node = ((qid >> 12) << 14) + ((qid & 4095) << 2);
    lfL[ql][j] = lfr[node * 9 + j];
  } else if (tid < 186){
    int t = tid - 146; int ql = t / 20, j = t - 20 * ql;
    nbrL[t] = nbr[(qid0 + ql) * 20 + j];
  }
  __syncthreads();
  #pragma unroll 1
  for (int p = 0; p < 10; p++){
    int e = (tid >> 6) + (p << 2), d = tid & 63;
    xs[e][d] = x[nbrL[e] * 64 + d];
  }
  __syncthreads();
  {
    int d = tid & 127;
    int cls, kk = 0, aa = 0;
    if (d < 64) cls = 0;
    else { int dd = d - 64;
      if (dd < 16) cls = 1;
      else { cls = 2; int r = dd - 16; kk = (r * 21846) >> 16; aa = r - 3 * kk; } }
    #pragma unroll 1
    for (int p = 0; p < 20; p++){
      int e = (tid >> 7) + (p << 1);
      int ql = (e >= 20) ? 1 : 0;
      float v;
      if (cls == 0) v = xdL[ql][d];
      else if (cls == 1) v = xs[e][d - 64] - xdL[ql][d - 64];
      else {
        int base = 16 + 3 * kk;
        float u0 = xs[e][base]     - xdL[ql][base];
        float u1 = xs[e][base + 1] - xdL[ql][base + 1];
        float u2 = xs[e][base + 2] - xdL[ql][base + 2];
        v = lfL[ql][aa * 3] * u0 + lfL[ql][aa * 3 + 1] * u1 + lfL[ql][aa * 3 + 2] * u2;
      }
      h[e][d] = v;
    }
  }
  __syncthreads();
  int eg = tid >> 7, og = tid & 127;
  {
    float acc1[20];
    float bv = b1[og];
    #pragma unroll
    for (int i = 0; i < 20; i++) acc1[i] = bv;
    for (int d0 = 0; d0 < 128; d0 += 4){
      float w0 = W1[(d0 + 0) * 128 + og];
      float w1 = W1[(d0 + 1) * 128 + og];
      float w2 = W1[(d0 + 2) * 128 + og];
      float w3 = W1[(d0 + 3) * 128 + og];
      #pragma unroll
      for (int i = 0; i < 20; i++){
        float4 hv = *(float4*)&h[eg * 20 + i][d0];
        acc1[i] += hv.x * w0 + hv.y * w1 + hv.z * w2 + hv.w * w3;
      }
    }
    #pragma unroll
    for (int i = 0; i < 20; i++) a1[eg * 20 + i][og] = fmaxf(acc1[i], 0.f);
  }
  __syncthreads();
  {
    float acc2[20];
    #pragma unroll
    for (int i = 0; i < 20; i++) acc2[i] = 0.f;
    for (int d0 = 0; d0 < 128; d0 += 4){
      float w0 = W2[(d0 + 0) * 128 + og];
      float w1 = W2[(d0 + 1) * 128 + og];
      float w2 = W2[(d0 + 2) * 128 + og];
      float w3 = W2[(d0 + 3) * 128 + og];
      #pragma unroll
      for (int i = 0; i < 20; i++){
        float4 av = *(float4*)&a1[eg * 20 + i][d0];
        acc2[i] += av.x * w0 + av.y * w1 + av.z * w2 + av.w * w3;
      }
    }
    float m = -3.0e38f;
    #pragma unroll
    for (int i = 0; i < 20; i++) m = fmaxf(m, acc2[i]);
    m += b2[og];
    out[(qid0 + eg) * 128 + og] = m;
  }
}

// ---------------------------------------------------------------------------
// k_tail: pos[idx], batch[idx], lframes[idx] as fp32 at flat offsets.
// ---------------------------------------------------------------------------
__global__ __launch_bounds__(256) void k_tail(const float* __restrict__ pos,
    const float* __restrict__ lfr, float* __restrict__ out){
  int q = blockIdx.x * 256 + threadIdx.x;   // 0..16383
  int b = q >> 12;
  int node = (b << 14) + ((q & 4095) << 2);
  float* o_pos = out + 2097152;    // 16384*128
  float* o_bat = out + 2146304;    // + 16384*3
  float* o_lf  = out + 2162688;    // + 16384
  #pragma unroll
  for (int j = 0; j < 3; j++) o_pos[q * 3 + j] = pos[node * 3 + j];
  o_bat[q] = (float)b;
  #pragma unroll
  for (int j = 0; j < 9; j++) o_lf[q * 9 + j] = lfr[node * 9 + j];
}

extern "C" void kernel_launch(void* const* d_in, const int* in_sizes, int n_in,
                              void* d_out, int out_size, void* d_ws, size_t ws_size,
                              hipStream_t stream){
  const float* x   = (const float*)d_in[0];
  const float* pos = (const float*)d_in[1];
  const float* lfr = (const float*)d_in[2];
  // d_in[3] = batch (recomputed analytically)
  const float* W1  = (const float*)d_in[4];
  const float* b1  = (const float*)d_in[5];
  const float* W2  = (const float*)d_in[6];
  const float* b2  = (const float*)d_in[7];

  unsigned short* kfB = (unsigned short*)d_ws;
  float* normB = (float*)((char*)d_ws + WS_NORM);
  int*   nbr   = (int*)((char*)d_ws + WS_NBR);
  float* out = (float*)d_out;

  hipLaunchKernelGGL(k_prep, dim3(256),  dim3(256), 0, stream, x, pos, lfr, kfB, normB);
  hipLaunchKernelGGL(k_knn,  dim3(256),  dim3(512), 0, stream, kfB, normB, x, pos, lfr, nbr);
  hipLaunchKernelGGL(k_mlp,  dim3(8192), dim3(256), 0, stream, x, lfr, nbr, W1, b1, W2, b2, out);
  hipLaunchKernelGGL(k_tail, dim3(64),   dim3(256), 0, stream, pos, lfr, out);
}

// Round 9
// 1122.227 us; speedup vs baseline: 1.1527x; 1.1492x over previous
//
#include <hip/hip_runtime.h>
#include <hip/hip_bf16.h>

// Problem constants
#define NTOT 65536      // B*N
#define KNN  20
#define CKEEP 32        // kept candidates for exact re-rank (margin over 20)
#define CAPB 384        // candidate rows: 96 + 256 worst-case + 32 stash
#define BPAD 65         // padded row width -> scan bank = (j+q)%32
#define HEADROOM 96     // compact when cnt > HEADROOM
#define KROW 104        // bf16 kf row stride (67 dims + pad)

typedef __attribute__((ext_vector_type(4))) float f32x4;
typedef __attribute__((ext_vector_type(8))) short s16x8;

// ws layout (bytes): kfB bf16[65536][104] | normB f32[65536] | nbr i32
#define WS_NORM 13631488
#define WS_NBR  13893632

// k_knn LDS map (bytes)
#define SMEM_KSQ 53248      // ksB @0 (53248), ksq @53248 (1024); scratch region [0,58880)
#define SMEM_BUF 58880      // unsigned buf[384][65] = 99840
#define SMEM_CNT 158720     // int cnt[64]
#define SMEM_TAU 158976     // float tau[64]
#define SMEM_SZ  159232
// re-rank overlay on scratch [0,58880): qkf dbl[64][67] @0 | rrD dbl[64][32] @34304 | rrI i32[64][32] @50688

__device__ __forceinline__ unsigned short f2bf_rne(float v){
  unsigned u = __float_as_uint(v);
  return (unsigned short)((u + 0x7FFFu + ((u >> 16) & 1u)) >> 16);
}

// ---------------------------------------------------------------------------
// k_prep: kf = [s(16), R^T v(48), pos(3)] -> bf16 rows (stride 104) + f32 norm
// ---------------------------------------------------------------------------
__global__ __launch_bounds__(256) void k_prep(const float* __restrict__ x,
        const float* __restrict__ pos, const float* __restrict__ lfr,
        unsigned short* __restrict__ kfB, float* __restrict__ normB){
  int n = blockIdx.x * 256 + threadIdx.x;
  const float* xr = x + n * 64;
  float R[9];
  #pragma unroll
  for (int j = 0; j < 9; j++) R[j] = lfr[n * 9 + j];
  float c[67];
  #pragma unroll
  for (int i = 0; i < 16; i++) c[i] = xr[i];
  #pragma unroll
  for (int k = 0; k < 16; k++){
    float v0 = xr[16 + 3*k], v1 = xr[17 + 3*k], v2 = xr[18 + 3*k];
    #pragma unroll
    for (int a = 0; a < 3; a++)
      c[16 + 3*k + a] = R[a] * v0 + R[3 + a] * v1 + R[6 + a] * v2;  // R^T v
  }
  #pragma unroll
  for (int a = 0; a < 3; a++) c[64 + a] = pos[n * 3 + a];
  float sq = 0.f;
  #pragma unroll
  for (int d = 0; d < 67; d++) sq += c[d] * c[d];
  __attribute__((aligned(16))) unsigned short row[KROW];
  #pragma unroll
  for (int d = 0; d < 67; d++) row[d] = f2bf_rne(c[d]);
  #pragma unroll
  for (int d = 67; d < KROW; d++) row[d] = 0;
  uint4* dst = (uint4*)(kfB + (size_t)n * KROW);
  const uint4* s4 = (const uint4*)row;
  #pragma unroll
  for (int i = 0; i < 13; i++) dst[i] = s4[i];
  normB[n] = sq;
}

// ---------------------------------------------------------------------------
// wave_compact: barrier-free exact top-32 for the wave's 8 queries.
// ---------------------------------------------------------------------------
__device__ __forceinline__ void wave_compact(unsigned (*buf)[BPAD],
    int* cnt, float* tau, int lane, int wv, int cmax){
  int q = (wv << 3) + (lane >> 3);
  int s = lane & 7;
  int cn = cnt[q];
  int mN = (cmax + 7) >> 3;          // chunk size (wave-uniform)
  int lo = s * mN;
  unsigned long long mask = 0ull;
  unsigned last = 0xFFFFFFFFu;
  #pragma unroll 1
  for (int r = 0; r < 32; r++){
    unsigned vmin = 0xFFFFFFFFu; int imin = -1;
    #pragma unroll 1
    for (int i = 0; i < mN; i++){
      int j = lo + i;
      unsigned v = (j < cn) ? buf[j][q] : 0xFFFFFFFFu;
      if (!((mask >> i) & 1ull) && v < vmin){ vmin = v; imin = i; }
    }
    unsigned bv = vmin;
    #pragma unroll
    for (int off = 1; off < 8; off <<= 1){
      unsigned ov = (unsigned)__shfl_xor((int)bv, off, 64);
      bv = (ov < bv) ? ov : bv;
    }
    if (vmin == bv && imin >= 0 && bv != 0xFFFFFFFFu) mask |= (1ull << (unsigned)imin);
    last = bv;
  }
  int kc = __popcll(mask);
  int incl = kc;
  #pragma unroll
  for (int d = 1; d < 8; d <<= 1){
    int t = __shfl_up(incl, d, 8);
    if (s >= d) incl += t;
  }
  int wr = cmax + (incl - kc);       // exclusive prefix over the 8 lanes
  #pragma unroll 1
  for (int i = 0; i < mN; i++){
    if ((mask >> i) & 1ull){
      buf[wr][q] = buf[lo + i][q];   // dest >= cmax > all sources: disjoint
      wr++;
    }
  }
  __builtin_amdgcn_s_waitcnt(0);     // stash visible within wave
  #pragma unroll
  for (int r = s; r < 32; r += 8){
    unsigned v = buf[cmax + r][q];
    buf[r][q] = v;
  }
  if (s == 0){ cnt[q] = 32; tau[q] = __uint_as_float(last & 0xFFFFC000u); }
  __builtin_amdgcn_s_waitcnt(0);
}

// ---------------------------------------------------------------------------
// k_knn: MFMA bf16 coarse distances + streaming top-K + exact fp64 re-rank.
// 512 thr, 1 block/CU (LDS-bound). Staging via __builtin_amdgcn_global_load_lds
// (async DMA, zero VGPR cost -- register prefetch spilled at the 128-VGPR cap
// of 512-thread blocks: r7/r8 WRITE_SIZE 373 MB). DMA for tile t+1 issued
// right after B2 (all ksB reads done), overlapping compaction; drained by the
// vmcnt(0) the compiler emits before B1's s_barrier.
// Appends live in [B1,B2]; per-wave compacts in [B2,B1] -- disjoint.
// ---------------------------------------------------------------------------
__global__ __launch_bounds__(512, 1) void k_knn(
    const unsigned short* __restrict__ kfB, const float* __restrict__ normB,
    const float* __restrict__ x, const float* __restrict__ pos,
    const float* __restrict__ lfr, int* __restrict__ nbr){
  __shared__ __attribute__((aligned(16))) char smem[SMEM_SZ];
  unsigned short* ksB = (unsigned short*)(smem);
  float* ksq = (float*)(smem + SMEM_KSQ);
  unsigned (*buf)[BPAD] = (unsigned (*)[BPAD])(smem + SMEM_BUF);
  int* cnt = (int*)(smem + SMEM_CNT);
  float* tau = (float*)(smem + SMEM_TAU);

  int tid = threadIdx.x;
  int blk = blockIdx.x;
  int b = (blk & 7) >> 1;
  int w = ((blk >> 3) << 1) | (blk & 1);   // 0..63 within batch
  int bbase = b << 14;
  int q0 = w << 6;

  if (tid < 64){ cnt[tid] = 0; tau[tid] = 3.0e38f; }

  int lane = tid & 63;
  int wv = tid >> 6;
  int l15 = lane & 15, quad = lane >> 4;

  // async-DMA one key tile (256 rows x 104 bf16 = 3328 x 16B, + 64 x 16B norms)
  auto issue_tile = [&](int tl){
    const char* gRow = (const char*)(kfB + (size_t)(bbase + (tl << 8)) * KROW);
    const char* gNrm = (const char*)(normB + bbase + (tl << 8));
    #pragma unroll
    for (int k2 = 0; k2 < 7; k2++){
      int i = tid + (k2 << 9);
      if (i < 3328){
        __builtin_amdgcn_global_load_lds(
            (const __attribute__((address_space(1))) void*)(gRow + (i << 4)),
            (__attribute__((address_space(3))) void*)((char*)ksB + (i << 4)),
            16, 0, 0);
      } else if (i < 3392){
        int j = i - 3328;
        __builtin_amdgcn_global_load_lds(
            (const __attribute__((address_space(1))) void*)(gNrm + (j << 4)),
            (__attribute__((address_space(3))) void*)((char*)ksq + (j << 4)),
            16, 0, 0);
      }
    }
  };

  // A fragments (4 m-tiles x 3 k-steps) + query norms, once per block
  s16x8 afr[4][3];
  float qsqv[4][4];
  #pragma unroll
  for (int mt = 0; mt < 4; mt++){
    int nodeA = bbase + ((q0 + mt * 16 + l15) << 2);
    #pragma unroll
    for (int ks = 0; ks < 3; ks++)
      afr[mt][ks] = *(const s16x8*)(kfB + (size_t)nodeA * KROW + ks * 32 + quad * 8);
    #pragma unroll
    for (int r = 0; r < 4; r++)
      qsqv[mt][r] = normB[bbase + ((q0 + mt * 16 + quad * 4 + r) << 2)];
  }

  issue_tile(0);
  __syncthreads();   // drains DMA(0); cnt/tau init visible

  const unsigned long long SCHED =
      (1ull<<1)|(1ull<<3)|(1ull<<7)|(1ull<<15)|(1ull<<31)|(1ull<<47);

  for (int tile = 0; tile < 64; ++tile){
    int kbase = tile << 8;

    float ksqv[2];
    #pragma unroll
    for (int jn = 0; jn < 2; jn++)
      ksqv[jn] = ksq[(wv * 2 + jn) * 16 + l15];

    f32x4 acc[4][2];
    #pragma unroll
    for (int mt = 0; mt < 4; mt++){
      acc[mt][0] = (f32x4){0.f,0.f,0.f,0.f};
      acc[mt][1] = (f32x4){0.f,0.f,0.f,0.f};
    }
    #pragma unroll
    for (int ks = 0; ks < 3; ks++){
      s16x8 bfr[2];
      #pragma unroll
      for (int jn = 0; jn < 2; jn++){
        int n = (wv * 2 + jn) * 16 + l15;
        bfr[jn] = *(const s16x8*)(ksB + n * KROW + ks * 32 + quad * 8);
      }
      #pragma unroll
      for (int mt = 0; mt < 4; mt++)
        #pragma unroll
        for (int jn = 0; jn < 2; jn++)
          acc[mt][jn] = __builtin_amdgcn_mfma_f32_16x16x32_bf16(
              afr[mt][ks], bfr[jn], acc[mt][jn], 0, 0, 0);
    }

    // epilogue: d2 + threshold-stream append (tau read direct from LDS)
    #pragma unroll
    for (int mt = 0; mt < 4; mt++){
      #pragma unroll
      for (int jn = 0; jn < 2; jn++){
        int kidx = kbase + (wv * 2 + jn) * 16 + l15;
        #pragma unroll
        for (int r = 0; r < 4; r++){
          int q = mt * 16 + quad * 4 + r;
          float d2 = fmaxf(qsqv[mt][r] + ksqv[jn] - 2.f * acc[mt][jn][r], 0.f);
          if (d2 < tau[q]){
            int pp = atomicAdd(&cnt[q], 1);
            buf[pp][q] = ((__float_as_uint(d2) + 0x2000u) & 0xFFFFC000u) | (unsigned)kidx;
          }
        }
      }
    }
    __syncthreads();   // B2: appends visible; ksB/ksq reads done
    if (tile < 63) issue_tile(tile + 1);   // DMA overlaps compaction below

    int cmax = cnt[(wv << 3) + (lane >> 3)];
    #pragma unroll
    for (int off = 8; off < 64; off <<= 1){
      int o = __shfl_xor(cmax, off, 64);
      cmax = o > cmax ? o : cmax;
    }
    if (cmax > HEADROOM || ((SCHED >> tile) & 1ull))
      wave_compact(buf, cnt, tau, lane, wv, cmax);
    __syncthreads();   // B1: drains DMA(t+1); compact results visible
  }
  // final exact compact -> rows 0..31 = coarse top-32 per query
  {
    int cmax = cnt[(wv << 3) + (lane >> 3)];
    #pragma unroll
    for (int off = 8; off < 64; off <<= 1){
      int o = __shfl_xor(cmax, off, 64);
      cmax = o > cmax ? o : cmax;
    }
    wave_compact(buf, cnt, tau, lane, wv, cmax);
  }
  __syncthreads();

  // ---- exact fp64 re-rank of the 32 survivors (kf rebuilt from raw inputs) ----
  double* qkf = (double*)(smem);
  double* rrD = (double*)(smem + 34304);
  int*    rrI = (int*)(smem + 50688);

  {  // rebuild query kf in fp64
    int t8 = tid & 7, q = tid >> 3;
    int node = bbase + ((q0 + q) << 2);
    const float* xr = x + node * 64;
    for (int dd = t8; dd < 67; dd += 8){
      double val;
      if (dd < 16) val = (double)xr[dd];
      else if (dd < 64){
        int r = dd - 16; int k = r / 3; int a = r - 3 * k;
        val = (double)lfr[node*9 + a]     * (double)xr[16 + 3*k]
            + (double)lfr[node*9 + 3 + a] * (double)xr[17 + 3*k]
            + (double)lfr[node*9 + 6 + a] * (double)xr[18 + 3*k];
      } else val = (double)pos[node*3 + (dd - 64)];
      qkf[q * 67 + dd] = val;
    }
  }
  __syncthreads();
  {  // candidate d2 in fp64
    int t8 = tid & 7, q = tid >> 3;
    for (int j = t8; j < CKEEP; j += 8){
      int idx = (int)(buf[j][q] & 0x3FFFu);
      int node = bbase + idx;
      const float* xr = x + node * 64;
      double R[9];
      #pragma unroll
      for (int t = 0; t < 9; t++) R[t] = (double)lfr[node * 9 + t];
      double d2 = 0.0;
      #pragma unroll
      for (int dd = 0; dd < 16; dd++){ double t = (double)xr[dd] - qkf[q*67 + dd]; d2 += t * t; }
      #pragma unroll
      for (int k = 0; k < 16; k++){
        double v0 = xr[16 + 3*k], v1 = xr[17 + 3*k], v2 = xr[18 + 3*k];
        #pragma unroll
        for (int a = 0; a < 3; a++){
          double val = R[a] * v0 + R[3 + a] * v1 + R[6 + a] * v2;
          double t = val - qkf[q*67 + 16 + 3*k + a]; d2 += t * t;
        }
      }
      #pragma unroll
      for (int a = 0; a < 3; a++){ double t = (double)pos[node*3 + a] - qkf[q*67 + 64 + a]; d2 += t * t; }
      rrD[q * CKEEP + j] = d2; rrI[q * CKEEP + j] = idx;
    }
  }
  __syncthreads();
  if (tid < 64){
    int qq = tid;
    int qid = (b << 12) + q0 + qq;
    #pragma unroll 1
    for (int s = 0; s < KNN; s++){
      double best = rrD[qq * CKEEP + s]; int bi = s;
      for (int t = s + 1; t < CKEEP; t++){
        double v = rrD[qq * CKEEP + t]; if (v < best){ best = v; bi = t; }
      }
      double tv = rrD[qq * CKEEP + bi]; rrD[qq * CKEEP + bi] = rrD[qq * CKEEP + s]; rrD[qq * CKEEP + s] = tv;
      int ti = rrI[qq * CKEEP + bi]; rrI[qq * CKEEP + bi] = rrI[qq * CKEEP + s]; rrI[qq * CKEEP + s] = ti;
      nbr[qid * KNN + s] = bbase + rrI[qq * CKEEP + s];
    }
  }
}

// ---------------------------------------------------------------------------
// k_mlp: 2 queries/block (40 edges). Gather x_src, build h=[x_dst, rel_local],
// relu(h@W1+b1)@W2, max over edges, +b2, fp32 store.
// ---------------------------------------------------------------------------
__global__ __launch_bounds__(256) void k_mlp(const float* __restrict__ x,
    const float* __restrict__ lfr, const int* __restrict__ nbr,
    const float* __restrict__ W1, const float* __restrict__ b1,
    const float* __restrict__ W2, const float* __restrict__ b2,
    float* __restrict__ out){
  __shared__ float xs[40][64];
  __shared__ float h[40][128];
  __shared__ float a1[40][128];
  __shared__ float xdL[2][64];
  __shared__ float lfL[2][9];
  __shared__ int nbrL[40];

  int tid = threadIdx.x;
  int qid0 = blockIdx.x * 2;
  if (tid < 128){
    int ql = tid >> 6, d = tid & 63;
    int qid = qid0 + ql;
    int node = ((qid >> 12) << 14) + ((qid & 4095) << 2);
    xdL[ql][d] = x[node * 64 + d];
  } else if (tid < 146){
    int t = tid - 128; int ql = t / 9, j = t - 9 * ql;
    int qid = qid0 + ql;
    int node = ((qid >> 12) << 14) + ((qid & 4095) << 2);
    lfL[ql][j] = lfr[node * 9 + j];
  } else if (tid < 186){
    int t = tid - 146; int ql = t / 20, j = t - 20 * ql;
    nbrL[t] = nbr[(qid0 + ql) * 20 + j];
  }
  __syncthreads();
  #pragma unroll 1
  for (int p = 0; p < 10; p++){
    int e = (tid >> 6) + (p << 2), d = tid & 63;
    xs[e][d] = x[nbrL[e] * 64 + d];
  }
  __syncthreads();
  {
    int d = tid & 127;
    int cls, kk = 0, aa = 0;
    if (d < 64) cls = 0;
    else { int dd = d - 64;
      if (dd < 16) cls = 1;
      else { cls = 2; int r = dd - 16; kk = (r * 21846) >> 16; aa = r - 3 * kk; } }
    #pragma unroll 1
    for (int p = 0; p < 20; p++){
      int e = (tid >> 7) + (p << 1);
      int ql = (e >= 20) ? 1 : 0;
      float v;
      if (cls == 0) v = xdL[ql][d];
      else if (cls == 1) v = xs[e][d - 64] - xdL[ql][d - 64];
      else {
        int base = 16 + 3 * kk;
        float u0 = xs[e][base]     - xdL[ql][base];
        float u1 = xs[e][base + 1] - xdL[ql][base + 1];
        float u2 = xs[e][base + 2] - xdL[ql][base + 2];
        v = lfL[ql][aa * 3] * u0 + lfL[ql][aa * 3 + 1] * u1 + lfL[ql][aa * 3 + 2] * u2;
      }
      h[e][d] = v;
    }
  }
  __syncthreads();
  int eg = tid >> 7, og = tid & 127;
  {
    float acc1[20];
    float bv = b1[og];
    #pragma unroll
    for (int i = 0; i < 20; i++) acc1[i] = bv;
    for (int d0 = 0; d0 < 128; d0 += 4){
      float w0 = W1[(d0 + 0) * 128 + og];
      float w1 = W1[(d0 + 1) * 128 + og];
      float w2 = W1[(d0 + 2) * 128 + og];
      float w3 = W1[(d0 + 3) * 128 + og];
      #pragma unroll
      for (int i = 0; i < 20; i++){
        float4 hv = *(float4*)&h[eg * 20 + i][d0];
        acc1[i] += hv.x * w0 + hv.y * w1 + hv.z * w2 + hv.w * w3;
      }
    }
    #pragma unroll
    for (int i = 0; i < 20; i++) a1[eg * 20 + i][og] = fmaxf(acc1[i], 0.f);
  }
  __syncthreads();
  {
    float acc2[20];
    #pragma unroll
    for (int i = 0; i < 20; i++) acc2[i] = 0.f;
    for (int d0 = 0; d0 < 128; d0 += 4){
      float w0 = W2[(d0 + 0) * 128 + og];
      float w1 = W2[(d0 + 1) * 128 + og];
      float w2 = W2[(d0 + 2) * 128 + og];
      float w3 = W2[(d0 + 3) * 128 + og];
      #pragma unroll
      for (int i = 0; i < 20; i++){
        float4 av = *(float4*)&a1[eg * 20 + i][d0];
        acc2[i] += av.x * w0 + av.y * w1 + av.z * w2 + av.w * w3;
      }
    }
    float m = -3.0e38f;
    #pragma unroll
    for (int i = 0; i < 20; i++) m = fmaxf(m, acc2[i]);
    m += b2[og];
    out[(qid0 + eg) * 128 + og] = m;
  }
}

// ---------------------------------------------------------------------------
// k_tail: pos[idx], batch[idx], lframes[idx] as fp32 at flat offsets.
// ---------------------------------------------------------------------------
__global__ __launch_bounds__(256) void k_tail(const float* __restrict__ pos,
    const float* __restrict__ lfr, float* __restrict__ out){
  int q = blockIdx.x * 256 + threadIdx.x;   // 0..16383
  int b = q >> 12;
  int node = (b << 14) + ((q & 4095) << 2);
  float* o_pos = out + 2097152;    // 16384*128
  float* o_bat = out + 2146304;    // + 16384*3
  float* o_lf  = out + 2162688;    // + 16384
  #pragma unroll
  for (int j = 0; j < 3; j++) o_pos[q * 3 + j] = pos[node * 3 + j];
  o_bat[q] = (float)b;
  #pragma unroll
  for (int j = 0; j < 9; j++) o_lf[q * 9 + j] = lfr[node * 9 + j];
}

extern "C" void kernel_launch(void* const* d_in, const int* in_sizes, int n_in,
                              void* d_out, int out_size, void* d_ws, size_t ws_size,
                              hipStream_t stream){
  const float* x   = (const float*)d_in[0];
  const float* pos = (const float*)d_in[1];
  const float* lfr = (const float*)d_in[2];
  // d_in[3] = batch (recomputed analytically)
  const float* W1  = (const float*)d_in[4];
  const float* b1  = (const float*)d_in[5];
  const float* W2  = (const float*)d_in[6];
  const float* b2  = (const float*)d_in[7];

  unsigned short* kfB = (unsigned short*)d_ws;
  float* normB = (float*)((char*)d_ws + WS_NORM);
  int*   nbr   = (int*)((char*)d_ws + WS_NBR);
  float* out = (float*)d_out;

  hipLaunchKernelGGL(k_prep, dim3(256),  dim3(256), 0, stream, x, pos, lfr, kfB, normB);
  hipLaunchKernelGGL(k_knn,  dim3(256),  dim3(512), 0, stream, kfB, normB, x, pos, lfr, nbr);
  hipLaunchKernelGGL(k_mlp,  dim3(8192), dim3(256), 0, stream, x, lfr, nbr, W1, b1, W2, b2, out);
  hipLaunchKernelGGL(k_tail, dim3(64),   dim3(256), 0, stream, pos, lfr, out);
}

// Round 10
// 823.014 us; speedup vs baseline: 1.5718x; 1.3636x over previous
//
#include <hip/hip_runtime.h>
#include <hip/hip_bf16.h>

// Problem constants
#define NTOT 65536      // B*N
#define KNN  20
#define CKEEP 32        // kept candidates for exact re-rank (margin over 20)
#define CAPB 384        // candidate rows: 96 + 256 worst-case + 32 stash
#define BPAD 65         // padded row width -> scan bank = (j+q)%32
#define HEADROOM 96     // compact when cnt > HEADROOM
#define KROW 104        // bf16 kf row stride (67 dims + pad)

typedef __attribute__((ext_vector_type(4))) float f32x4;
typedef __attribute__((ext_vector_type(8))) short s16x8;

// ws layout (bytes): kfB bf16[65536][104] | normB f32[65536] | nbr i32
#define WS_NORM 13631488
#define WS_NBR  13893632

// k_knn LDS map (bytes)
#define SMEM_KSQ 53248      // ksB @0 (53248), ksq @53248 (1024); scratch region [0,58880)
#define SMEM_BUF 58880      // unsigned buf[384][65] = 99840
#define SMEM_CNT 158720     // int cnt[64]
#define SMEM_TAU 158976     // float tau[64]
#define SMEM_SZ  159232

__device__ __forceinline__ unsigned short f2bf_rne(float v){
  unsigned u = __float_as_uint(v);
  return (unsigned short)((u + 0x7FFFu + ((u >> 16) & 1u)) >> 16);
}

// ---------------------------------------------------------------------------
// k_prep: kf = [s(16), R^T v(48), pos(3)] -> bf16 rows (stride 104) + f32 norm
// ---------------------------------------------------------------------------
__global__ __launch_bounds__(256) void k_prep(const float* __restrict__ x,
        const float* __restrict__ pos, const float* __restrict__ lfr,
        unsigned short* __restrict__ kfB, float* __restrict__ normB){
  int n = blockIdx.x * 256 + threadIdx.x;
  const float* xr = x + n * 64;
  float R[9];
  #pragma unroll
  for (int j = 0; j < 9; j++) R[j] = lfr[n * 9 + j];
  float c[67];
  #pragma unroll
  for (int i = 0; i < 16; i++) c[i] = xr[i];
  #pragma unroll
  for (int k = 0; k < 16; k++){
    float v0 = xr[16 + 3*k], v1 = xr[17 + 3*k], v2 = xr[18 + 3*k];
    #pragma unroll
    for (int a = 0; a < 3; a++)
      c[16 + 3*k + a] = R[a] * v0 + R[3 + a] * v1 + R[6 + a] * v2;  // R^T v
  }
  #pragma unroll
  for (int a = 0; a < 3; a++) c[64 + a] = pos[n * 3 + a];
  float sq = 0.f;
  #pragma unroll
  for (int d = 0; d < 67; d++) sq += c[d] * c[d];
  __attribute__((aligned(16))) unsigned short row[KROW];
  #pragma unroll
  for (int d = 0; d < 67; d++) row[d] = f2bf_rne(c[d]);
  #pragma unroll
  for (int d = 67; d < KROW; d++) row[d] = 0;
  uint4* dst = (uint4*)(kfB + (size_t)n * KROW);
  const uint4* s4 = (const uint4*)row;
  #pragma unroll
  for (int i = 0; i < 13; i++) dst[i] = s4[i];
  normB[n] = sq;
}

// ---------------------------------------------------------------------------
// wave_compact: barrier-free exact top-32 for the wave's 8 queries.
// ---------------------------------------------------------------------------
__device__ __forceinline__ void wave_compact(unsigned (*buf)[BPAD],
    int* cnt, float* tau, int lane, int wv, int cmax){
  int q = (wv << 3) + (lane >> 3);
  int s = lane & 7;
  int cn = cnt[q];
  int mN = (cmax + 7) >> 3;          // chunk size (wave-uniform)
  int lo = s * mN;
  unsigned long long mask = 0ull;
  unsigned last = 0xFFFFFFFFu;
  #pragma unroll 1
  for (int r = 0; r < 32; r++){
    unsigned vmin = 0xFFFFFFFFu; int imin = -1;
    #pragma unroll 1
    for (int i = 0; i < mN; i++){
      int j = lo + i;
      unsigned v = (j < cn) ? buf[j][q] : 0xFFFFFFFFu;
      if (!((mask >> i) & 1ull) && v < vmin){ vmin = v; imin = i; }
    }
    unsigned bv = vmin;
    #pragma unroll
    for (int off = 1; off < 8; off <<= 1){
      unsigned ov = (unsigned)__shfl_xor((int)bv, off, 64);
      bv = (ov < bv) ? ov : bv;
    }
    if (vmin == bv && imin >= 0 && bv != 0xFFFFFFFFu) mask |= (1ull << (unsigned)imin);
    last = bv;
  }
  int kc = __popcll(mask);
  int incl = kc;
  #pragma unroll
  for (int d = 1; d < 8; d <<= 1){
    int t = __shfl_up(incl, d, 8);
    if (s >= d) incl += t;
  }
  int wr = cmax + (incl - kc);       // exclusive prefix over the 8 lanes
  #pragma unroll 1
  for (int i = 0; i < mN; i++){
    if ((mask >> i) & 1ull){
      buf[wr][q] = buf[lo + i][q];   // dest >= cmax > all sources: disjoint
      wr++;
    }
  }
  __builtin_amdgcn_s_waitcnt(0);     // stash visible within wave
  #pragma unroll
  for (int r = s; r < 32; r += 8){
    unsigned v = buf[cmax + r][q];
    buf[r][q] = v;
  }
  if (s == 0){ cnt[q] = 32; tau[q] = __uint_as_float(last & 0xFFFFC000u); }
  __builtin_amdgcn_s_waitcnt(0);
}

// ---------------------------------------------------------------------------
// k_knn: unchanged from r9 (593 us). MFMA coarse + stream top-K + fp64 rerank.
// ---------------------------------------------------------------------------
__global__ __launch_bounds__(512, 1) void k_knn(
    const unsigned short* __restrict__ kfB, const float* __restrict__ normB,
    const float* __restrict__ x, const float* __restrict__ pos,
    const float* __restrict__ lfr, int* __restrict__ nbr){
  __shared__ __attribute__((aligned(16))) char smem[SMEM_SZ];
  unsigned short* ksB = (unsigned short*)(smem);
  float* ksq = (float*)(smem + SMEM_KSQ);
  unsigned (*buf)[BPAD] = (unsigned (*)[BPAD])(smem + SMEM_BUF);
  int* cnt = (int*)(smem + SMEM_CNT);
  float* tau = (float*)(smem + SMEM_TAU);

  int tid = threadIdx.x;
  int blk = blockIdx.x;
  int b = (blk & 7) >> 1;
  int w = ((blk >> 3) << 1) | (blk & 1);   // 0..63 within batch
  int bbase = b << 14;
  int q0 = w << 6;

  if (tid < 64){ cnt[tid] = 0; tau[tid] = 3.0e38f; }

  int lane = tid & 63;
  int wv = tid >> 6;
  int l15 = lane & 15, quad = lane >> 4;

  auto issue_tile = [&](int tl){
    const char* gRow = (const char*)(kfB + (size_t)(bbase + (tl << 8)) * KROW);
    const char* gNrm = (const char*)(normB + bbase + (tl << 8));
    #pragma unroll
    for (int k2 = 0; k2 < 7; k2++){
      int i = tid + (k2 << 9);
      if (i < 3328){
        __builtin_amdgcn_global_load_lds(
            (const __attribute__((address_space(1))) void*)(gRow + (i << 4)),
            (__attribute__((address_space(3))) void*)((char*)ksB + (i << 4)),
            16, 0, 0);
      } else if (i < 3392){
        int j = i - 3328;
        __builtin_amdgcn_global_load_lds(
            (const __attribute__((address_space(1))) void*)(gNrm + (j << 4)),
            (__attribute__((address_space(3))) void*)((char*)ksq + (j << 4)),
            16, 0, 0);
      }
    }
  };

  s16x8 afr[4][3];
  float qsqv[4][4];
  #pragma unroll
  for (int mt = 0; mt < 4; mt++){
    int nodeA = bbase + ((q0 + mt * 16 + l15) << 2);
    #pragma unroll
    for (int ks = 0; ks < 3; ks++)
      afr[mt][ks] = *(const s16x8*)(kfB + (size_t)nodeA * KROW + ks * 32 + quad * 8);
    #pragma unroll
    for (int r = 0; r < 4; r++)
      qsqv[mt][r] = normB[bbase + ((q0 + mt * 16 + quad * 4 + r) << 2)];
  }

  issue_tile(0);
  __syncthreads();

  const unsigned long long SCHED =
      (1ull<<1)|(1ull<<3)|(1ull<<7)|(1ull<<15)|(1ull<<31)|(1ull<<47);

  for (int tile = 0; tile < 64; ++tile){
    int kbase = tile << 8;

    float ksqv[2];
    #pragma unroll
    for (int jn = 0; jn < 2; jn++)
      ksqv[jn] = ksq[(wv * 2 + jn) * 16 + l15];

    f32x4 acc[4][2];
    #pragma unroll
    for (int mt = 0; mt < 4; mt++){
      acc[mt][0] = (f32x4){0.f,0.f,0.f,0.f};
      acc[mt][1] = (f32x4){0.f,0.f,0.f,0.f};
    }
    #pragma unroll
    for (int ks = 0; ks < 3; ks++){
      s16x8 bfr[2];
      #pragma unroll
      for (int jn = 0; jn < 2; jn++){
        int n = (wv * 2 + jn) * 16 + l15;
        bfr[jn] = *(const s16x8*)(ksB + n * KROW + ks * 32 + quad * 8);
      }
      #pragma unroll
      for (int mt = 0; mt < 4; mt++)
        #pragma unroll
        for (int jn = 0; jn < 2; jn++)
          acc[mt][jn] = __builtin_amdgcn_mfma_f32_16x16x32_bf16(
              afr[mt][ks], bfr[jn], acc[mt][jn], 0, 0, 0);
    }

    #pragma unroll
    for (int mt = 0; mt < 4; mt++){
      #pragma unroll
      for (int jn = 0; jn < 2; jn++){
        int kidx = kbase + (wv * 2 + jn) * 16 + l15;
        #pragma unroll
        for (int r = 0; r < 4; r++){
          int q = mt * 16 + quad * 4 + r;
          float d2 = fmaxf(qsqv[mt][r] + ksqv[jn] - 2.f * acc[mt][jn][r], 0.f);
          if (d2 < tau[q]){
            int pp = atomicAdd(&cnt[q], 1);
            buf[pp][q] = ((__float_as_uint(d2) + 0x2000u) & 0xFFFFC000u) | (unsigned)kidx;
          }
        }
      }
    }
    __syncthreads();   // B2: appends visible; ksB/ksq reads done
    if (tile < 63) issue_tile(tile + 1);

    int cmax = cnt[(wv << 3) + (lane >> 3)];
    #pragma unroll
    for (int off = 8; off < 64; off <<= 1){
      int o = __shfl_xor(cmax, off, 64);
      cmax = o > cmax ? o : cmax;
    }
    if (cmax > HEADROOM || ((SCHED >> tile) & 1ull))
      wave_compact(buf, cnt, tau, lane, wv, cmax);
    __syncthreads();   // B1: drains DMA(t+1); compact results visible
  }
  {
    int cmax = cnt[(wv << 3) + (lane >> 3)];
    #pragma unroll
    for (int off = 8; off < 64; off <<= 1){
      int o = __shfl_xor(cmax, off, 64);
      cmax = o > cmax ? o : cmax;
    }
    wave_compact(buf, cnt, tau, lane, wv, cmax);
  }
  __syncthreads();

  double* qkf = (double*)(smem);
  double* rrD = (double*)(smem + 34304);
  int*    rrI = (int*)(smem + 50688);

  {
    int t8 = tid & 7, q = tid >> 3;
    int node = bbase + ((q0 + q) << 2);
    const float* xr = x + node * 64;
    for (int dd = t8; dd < 67; dd += 8){
      double val;
      if (dd < 16) val = (double)xr[dd];
      else if (dd < 64){
        int r = dd - 16; int k = r / 3; int a = r - 3 * k;
        val = (double)lfr[node*9 + a]     * (double)xr[16 + 3*k]
            + (double)lfr[node*9 + 3 + a] * (double)xr[17 + 3*k]
            + (double)lfr[node*9 + 6 + a] * (double)xr[18 + 3*k];
      } else val = (double)pos[node*3 + (dd - 64)];
      qkf[q * 67 + dd] = val;
    }
  }
  __syncthreads();
  {
    int t8 = tid & 7, q = tid >> 3;
    for (int j = t8; j < CKEEP; j += 8){
      int idx = (int)(buf[j][q] & 0x3FFFu);
      int node = bbase + idx;
      const float* xr = x + node * 64;
      double R[9];
      #pragma unroll
      for (int t = 0; t < 9; t++) R[t] = (double)lfr[node * 9 + t];
      double d2 = 0.0;
      #pragma unroll
      for (int dd = 0; dd < 16; dd++){ double t = (double)xr[dd] - qkf[q*67 + dd]; d2 += t * t; }
      #pragma unroll
      for (int k = 0; k < 16; k++){
        double v0 = xr[16 + 3*k], v1 = xr[17 + 3*k], v2 = xr[18 + 3*k];
        #pragma unroll
        for (int a = 0; a < 3; a++){
          double val = R[a] * v0 + R[3 + a] * v1 + R[6 + a] * v2;
          double t = val - qkf[q*67 + 16 + 3*k + a]; d2 += t * t;
        }
      }
      #pragma unroll
      for (int a = 0; a < 3; a++){ double t = (double)pos[node*3 + a] - qkf[q*67 + 64 + a]; d2 += t * t; }
      rrD[q * CKEEP + j] = d2; rrI[q * CKEEP + j] = idx;
    }
  }
  __syncthreads();
  if (tid < 64){
    int qq = tid;
    int qid = (b << 12) + q0 + qq;
    #pragma unroll 1
    for (int s = 0; s < KNN; s++){
      double best = rrD[qq * CKEEP + s]; int bi = s;
      for (int t = s + 1; t < CKEEP; t++){
        double v = rrD[qq * CKEEP + t]; if (v < best){ best = v; bi = t; }
      }
      double tv = rrD[qq * CKEEP + bi]; rrD[qq * CKEEP + bi] = rrD[qq * CKEEP + s]; rrD[qq * CKEEP + s] = tv;
      int ti = rrI[qq * CKEEP + bi]; rrI[qq * CKEEP + bi] = rrI[qq * CKEEP + s]; rrI[qq * CKEEP + s] = ti;
      nbr[qid * KNN + s] = bbase + rrI[qq * CKEEP + s];
    }
  }
}

// ---------------------------------------------------------------------------
// k_mlp (MFMA rewrite): 8 queries/block = 160 edge-rows (10 m-tiles), 512 thr
// (8 waves, wave wv owns 16 output cols). bf16 MFMA both layers, fp32 acc.
// LDS k-blocked layouts [k/32][row][32] (16B-aligned b128 frags, 2-way banks).
// Max-over-20-edges fully in registers via compile-time query-boundary masks.
// ---------------------------------------------------------------------------
#define M_X   0         // xs f32[160][68] = 43520 ; later Wt2 bf16[4][128][32]
#define M_H   43520     // hB bf16[4][160][32] = 40960
#define M_A1  84480     // a1B bf16[4][160][32] = 40960 (early: nbrL/xdL/lfL overlay)
#define M_W   125440    // Wt1 bf16[4][128][32] = 32768
#define M_B1  158208    // b1 f32[128]
#define M_B2  158720    // b2 f32[128]
#define M_SZ  159232

__global__ __launch_bounds__(512) void k_mlp(const float* __restrict__ x,
    const float* __restrict__ lfr, const int* __restrict__ nbr,
    const float* __restrict__ W1, const float* __restrict__ b1,
    const float* __restrict__ W2, const float* __restrict__ b2,
    float* __restrict__ out){
  __shared__ __attribute__((aligned(16))) char smem[M_SZ];
  float* xsF = (float*)(smem + M_X);
  unsigned short* hB = (unsigned short*)(smem + M_H);
  unsigned short* a1B = (unsigned short*)(smem + M_A1);
  unsigned short* wt1 = (unsigned short*)(smem + M_W);
  unsigned short* wt2 = (unsigned short*)(smem + M_X);
  float* b1L = (float*)(smem + M_B1);
  float* b2L = (float*)(smem + M_B2);
  int*   nbrL = (int*)(smem + M_A1);            // overlay (dead before a1 writes)
  float* xdL  = (float*)(smem + M_A1 + 640);    // 8x64 f32
  float* lfL  = (float*)(smem + M_A1 + 2688);   // 8x9 f32

  int tid = threadIdx.x;
  int qid0 = blockIdx.x * 8;
  int lane = tid & 63, wv = tid >> 6;
  int l15 = lane & 15, quad = lane >> 4;

  // ---- init loads ----
  if (tid < 160) nbrL[tid] = nbr[qid0 * 20 + tid];
  {
    int q = tid >> 6, d = tid & 63;
    int qid = qid0 + q;
    int node = ((qid >> 12) << 14) + ((qid & 4095) << 2);
    xdL[q * 64 + d] = x[node * 64 + d];
  }
  if (tid < 72){
    int q = tid / 9, j = tid - 9 * q;
    int qid = qid0 + q;
    int node = ((qid >> 12) << 14) + ((qid & 4095) << 2);
    lfL[q * 9 + j] = lfr[node * 9 + j];
  }
  if (tid < 128){ b1L[tid] = b1[tid]; b2L[tid] = b2[tid]; }
  __syncthreads();

  // ---- gather x_src into xs (160 rows x 64 f32, stride 68) ----
  {
    int f4 = tid & 15;
    #pragma unroll
    for (int p = 0; p < 5; p++){
      int e = (tid >> 4) + (p << 5);
      float4 v = *(const float4*)&x[(size_t)nbrL[e] * 64 + (f4 << 2)];
      *(float4*)&xsF[e * 68 + (f4 << 2)] = v;
    }
  }
  __syncthreads();

  // ---- build h bf16 into hB [d>>5][e][d&31] ----
  {
    int d = tid & 127, eo = tid >> 7;   // eo 0..3
    int cls, kk = 0, aa = 0;
    if (d < 64) cls = 0;
    else { int dd = d - 64;
      if (dd < 16) cls = 1;
      else { cls = 2; int r = dd - 16; kk = (r * 21846) >> 16; aa = r - 3 * kk; } }
    int hoff = ((d >> 5) * 160) * 32 + (d & 31);
    #pragma unroll 4
    for (int p = 0; p < 40; p++){
      int e = eo + (p << 2);
      int q = (e * 3277) >> 16;       // e/20 for e<160
      float v;
      if (cls == 0) v = xdL[q * 64 + d];
      else if (cls == 1) v = xsF[e * 68 + (d - 64)] - xdL[q * 64 + (d - 64)];
      else {
        int base = 16 + 3 * kk;
        float u0 = xsF[e * 68 + base]     - xdL[q * 64 + base];
        float u1 = xsF[e * 68 + base + 1] - xdL[q * 64 + base + 1];
        float u2 = xsF[e * 68 + base + 2] - xdL[q * 64 + base + 2];
        v = lfL[q * 9 + aa * 3] * u0 + lfL[q * 9 + aa * 3 + 1] * u1 + lfL[q * 9 + aa * 3 + 2] * u2;
      }
      hB[hoff + e * 32] = f2bf_rne(v);
    }
  }
  __syncthreads();   // hB done; xs/xdL/lfL/nbrL dead

  // ---- stage Wt1 -> M_W, Wt2 -> M_X  (layout [k>>5][n][32], value W[k][n]) ----
  #pragma unroll 4
  for (int i = tid; i < 16384; i += 512){
    int k = i >> 7, n = i & 127;
    int a = ((k >> 5) * 128 + n) * 32 + (k & 31);
    wt1[a] = f2bf_rne(W1[i]);
    wt2[a] = f2bf_rne(W2[i]);
  }
  __syncthreads();   // weights visible

  // ---- layer 1: a1 = relu(h @ W1 + b1) ----
  {
    s16x8 bfr[4];
    #pragma unroll
    for (int ks = 0; ks < 4; ks++)
      bfr[ks] = *(const s16x8*)(wt1 + ((ks * 128 + (wv << 4) + l15) * 32 + (quad << 3)));
    float b1v = b1L[(wv << 4) + l15];
    int colhi = wv >> 1, collo = ((wv & 1) << 4) + l15;
    #pragma unroll
    for (int mt = 0; mt < 10; mt++){
      f32x4 acc = (f32x4){0.f, 0.f, 0.f, 0.f};
      #pragma unroll
      for (int ks = 0; ks < 4; ks++){
        s16x8 af = *(const s16x8*)(hB + ((ks * 160 + (mt << 4) + l15) * 32 + (quad << 3)));
        acc = __builtin_amdgcn_mfma_f32_16x16x32_bf16(af, bfr[ks], acc, 0, 0, 0);
      }
      #pragma unroll
      for (int r = 0; r < 4; r++){
        float v = fmaxf(acc[r] + b1v, 0.f);
        int row = (mt << 4) + (quad << 2) + r;
        a1B[(colhi * 160 + row) * 32 + collo] = f2bf_rne(v);
      }
    }
  }
  __syncthreads();   // a1 complete

  // ---- layer 2 + max over edges (registers only) ----
  {
    s16x8 bfr[4];
    #pragma unroll
    for (int ks = 0; ks < 4; ks++)
      bfr[ks] = *(const s16x8*)(wt2 + ((ks * 128 + (wv << 4) + l15) * 32 + (quad << 3)));
    float mxv[8];
    #pragma unroll
    for (int q = 0; q < 8; q++) mxv[q] = -3.0e38f;
    const int QA[10]  = {0,0,1,2,3,4,4,5,6,7};
    const int CUT[10] = {16,4,8,12,16,16,4,8,12,16};
    #pragma unroll
    for (int mt = 0; mt < 10; mt++){
      f32x4 acc = (f32x4){0.f, 0.f, 0.f, 0.f};
      #pragma unroll
      for (int ks = 0; ks < 4; ks++){
        s16x8 af = *(const s16x8*)(a1B + ((ks * 160 + (mt << 4) + l15) * 32 + (quad << 3)));
        acc = __builtin_amdgcn_mfma_f32_16x16x32_bf16(af, bfr[ks], acc, 0, 0, 0);
      }
      int qa = QA[mt], cut = CUT[mt];
      if (cut >= 16){
        #pragma unroll
        for (int r = 0; r < 4; r++) mxv[qa] = fmaxf(mxv[qa], acc[r]);
      } else {
        #pragma unroll
        for (int r = 0; r < 4; r++){
          int lr = (quad << 2) + r;
          bool toA = lr < cut;
          mxv[qa]     = fmaxf(mxv[qa],     toA ? acc[r] : -3.0e38f);
          mxv[qa + 1] = fmaxf(mxv[qa + 1], toA ? -3.0e38f : acc[r]);
        }
      }
    }
    // combine across quads (rows) -- all lanes end with full per-col max
    #pragma unroll
    for (int q = 0; q < 8; q++){
      float v = mxv[q];
      v = fmaxf(v, __shfl_xor(v, 16, 64));
      v = fmaxf(v, __shfl_xor(v, 32, 64));
      mxv[q] = v;
    }
    if (quad == 0){
      int col = (wv << 4) + l15;
      float b2v = b2L[col];
      #pragma unroll
      for (int q = 0; q < 8; q++)
        out[(size_t)(qid0 + q) * 128 + col] = mxv[q] + b2v;
    }
  }
}

// ---------------------------------------------------------------------------
// k_tail: pos[idx], batch[idx], lframes[idx] as fp32 at flat offsets.
// ---------------------------------------------------------------------------
__global__ __launch_bounds__(256) void k_tail(const float* __restrict__ pos,
    const float* __restrict__ lfr, float* __restrict__ out){
  int q = blockIdx.x * 256 + threadIdx.x;   // 0..16383
  int b = q >> 12;
  int node = (b << 14) + ((q & 4095) << 2);
  float* o_pos = out + 2097152;    // 16384*128
  float* o_bat = out + 2146304;    // + 16384*3
  float* o_lf  = out + 2162688;    // + 16384
  #pragma unroll
  for (int j = 0; j < 3; j++) o_pos[q * 3 + j] = pos[node * 3 + j];
  o_bat[q] = (float)b;
  #pragma unroll
  for (int j = 0; j < 9; j++) o_lf[q * 9 + j] = lfr[node * 9 + j];
}

extern "C" void kernel_launch(void* const* d_in, const int* in_sizes, int n_in,
                              void* d_out, int out_size, void* d_ws, size_t ws_size,
                              hipStream_t stream){
  const float* x   = (const float*)d_in[0];
  const float* pos = (const float*)d_in[1];
  const float* lfr = (const float*)d_in[2];
  // d_in[3] = batch (recomputed analytically)
  const float* W1  = (const float*)d_in[4];
  const float* b1  = (const float*)d_in[5];
  const float* W2  = (const float*)d_in[6];
  const float* b2  = (const float*)d_in[7];

  unsigned short* kfB = (unsigned short*)d_ws;
  float* normB = (float*)((char*)d_ws + WS_NORM);
  int*   nbr   = (int*)((char*)d_ws + WS_NBR);
  float* out = (float*)d_out;

  hipLaunchKernelGGL(k_prep, dim3(256),  dim3(256), 0, stream, x, pos, lfr, kfB, normB);
  hipLaunchKernelGGL(k_knn,  dim3(256),  dim3(512), 0, stream, kfB, normB, x, pos, lfr, nbr);
  hipLaunchKernelGGL(k_mlp,  dim3(2048), dim3(512), 0, stream, x, lfr, nbr, W1, b1, W2, b2, out);
  hipLaunchKernelGGL(k_tail, dim3(64),   dim3(256), 0, stream, pos, lfr, out);
}